// Round 1
// baseline (5900.163 us; speedup 1.0000x reference)
//
#include <hip/hip_runtime.h>

// Model: B=32, L1=512, L2=16, D=300, H=300, V=50000, C=3
#define B_  32
#define L1_ 512
#define L2_ 16
#define D_  300
#define H_  300

__device__ __forceinline__ float sigmoid_fast(float x) {
    return 1.0f / (1.0f + __expf(-x));
}
__device__ __forceinline__ float tanh_fast(float x) {
    x = fminf(fmaxf(x, -15.0f), 15.0f);
    float e = __expf(2.0f * x);
    return (e - 1.0f) / (e + 1.0f);
}
__device__ __forceinline__ float wred_sum(float v) {
    #pragma unroll
    for (int off = 32; off > 0; off >>= 1) v += __shfl_xor(v, off);
    return v;
}
__device__ __forceinline__ float wred_max(float v) {
    #pragma unroll
    for (int off = 32; off > 0; off >>= 1) v = fmaxf(v, __shfl_xor(v, off));
    return v;
}

// ---------------- gather rows of emb (row length 300 = 75 float4) ----------------
__global__ __launch_bounds__(256) void gather_kernel(const float* __restrict__ emb,
                                                     const int* __restrict__ ids,
                                                     float* __restrict__ out, int total) {
    for (int i = blockIdx.x * 256 + threadIdx.x; i < total; i += gridDim.x * 256) {
        int row = i / 75, c = i % 75;
        int id = ids[row];
        reinterpret_cast<float4*>(out)[i] =
            reinterpret_cast<const float4*>(emb + (size_t)id * 300)[c];
    }
}

// ---------------- transpose whh (900x300) -> whhT (300x900) ----------------
__global__ __launch_bounds__(256) void transpose_kernel(const float* __restrict__ src,
                                                        float* __restrict__ dst) {
    int i = blockIdx.x * 256 + threadIdx.x;
    if (i < 900 * 300) {
        int r = i / 300, k = i % 300;
        dst[k * 900 + r] = src[i];
    }
}

// ---------------- fp32 GEMM: C[M,N] = A[M,K] @ W[N,K]^T (+ bias[n]) ----------------
// M multiple of 128. N,K arbitrary (K%4==0).
#define TM 128
#define TN 64
#define TK 16
__global__ __launch_bounds__(256) void gemm_nt(const float* __restrict__ A,
                                               const float* __restrict__ W,
                                               const float* __restrict__ bias,
                                               float* __restrict__ C,
                                               int M, int N, int K) {
    __shared__ __align__(16) float As[TK][TM + 4];
    __shared__ __align__(16) float Bs[TK][TN + 4];
    const int tid = threadIdx.x;
    const int m0 = blockIdx.x * TM;
    const int n0 = blockIdx.y * TN;
    const int tx = tid & 15;        // 16 * 4 = 64 cols
    const int ty = tid >> 4;        // 16 * 8 = 128 rows
    const int lr = tid >> 2;        // 0..63
    const int lk = (tid & 3) << 2;  // 0,4,8,12

    float acc[8][4];
    #pragma unroll
    for (int i = 0; i < 8; ++i)
        #pragma unroll
        for (int j = 0; j < 4; ++j) acc[i][j] = 0.f;

    for (int k0 = 0; k0 < K; k0 += TK) {
        const bool kok = (k0 + lk + 3) < K;
        #pragma unroll
        for (int h = 0; h < 2; ++h) {
            float4 v = make_float4(0.f, 0.f, 0.f, 0.f);
            int m = m0 + lr + 64 * h;
            if (kok) v = *reinterpret_cast<const float4*>(&A[(size_t)m * K + k0 + lk]);
            As[lk + 0][lr + 64 * h] = v.x;
            As[lk + 1][lr + 64 * h] = v.y;
            As[lk + 2][lr + 64 * h] = v.z;
            As[lk + 3][lr + 64 * h] = v.w;
        }
        {
            float4 v = make_float4(0.f, 0.f, 0.f, 0.f);
            int n = n0 + lr;
            if (kok && n < N) v = *reinterpret_cast<const float4*>(&W[(size_t)n * K + k0 + lk]);
            Bs[lk + 0][lr] = v.x;
            Bs[lk + 1][lr] = v.y;
            Bs[lk + 2][lr] = v.z;
            Bs[lk + 3][lr] = v.w;
        }
        __syncthreads();
        #pragma unroll
        for (int k = 0; k < TK; ++k) {
            float4 a0 = *reinterpret_cast<const float4*>(&As[k][ty * 8]);
            float4 a1 = *reinterpret_cast<const float4*>(&As[k][ty * 8 + 4]);
            float4 bv = *reinterpret_cast<const float4*>(&Bs[k][tx * 4]);
            float av[8] = {a0.x, a0.y, a0.z, a0.w, a1.x, a1.y, a1.z, a1.w};
            float bb[4] = {bv.x, bv.y, bv.z, bv.w};
            #pragma unroll
            for (int i = 0; i < 8; ++i)
                #pragma unroll
                for (int j = 0; j < 4; ++j) acc[i][j] += av[i] * bb[j];
        }
        __syncthreads();
    }
    #pragma unroll
    for (int i = 0; i < 8; ++i) {
        int m = m0 + ty * 8 + i;
        #pragma unroll
        for (int j = 0; j < 4; ++j) {
            int n = n0 + tx * 4 + j;
            if (n < N) C[(size_t)m * N + n] = acc[i][j] + (bias ? bias[n] : 0.f);
        }
    }
}

// ---------------- attention: scores -> alpha -> context_ -> beta logits ----------------
// block = (chunk of 16 l, b); 4 waves x 4 l each.
__global__ __launch_bounds__(256) void attn_kernel(const float* __restrict__ c_proj,
                                                   const float* __restrict__ a_proj,
                                                   const float* __restrict__ asp_emb,
                                                   const float* __restrict__ lin,
                                                   const float* __restrict__ Vatt,
                                                   const float* __restrict__ Vw,
                                                   const float* __restrict__ bVw,
                                                   float* __restrict__ blogit) {
    const int b = blockIdx.y;
    const int chunk = blockIdx.x;
    __shared__ float sA[16 * 300];
    __shared__ float sE[16 * 300];
    __shared__ float sV[300];
    __shared__ float sW[300];
    const int tid = threadIdx.x;
    for (int i = tid; i < 16 * 300; i += 256) {
        sA[i] = a_proj[b * 4800 + i];
        sE[i] = asp_emb[b * 4800 + i];
    }
    for (int i = tid; i < 300; i += 256) {
        sV[i] = Vatt[i];
        sW[i] = Vw[i];
    }
    __syncthreads();
    const int wave = tid >> 6, lane = tid & 63;
    const float bvw = bVw[0];
    for (int li = 0; li < 4; ++li) {
        const int l = chunk * 16 + wave * 4 + li;
        const float* crow = c_proj + (size_t)(b * L1_ + l) * 300;
        float cr[5];
        #pragma unroll
        for (int i = 0; i < 5; ++i) {
            int d = lane + 64 * i;
            cr[i] = (d < 300) ? crow[d] : 0.f;
        }
        float sc[16];
        #pragma unroll
        for (int m = 0; m < 16; ++m) {
            float s = 0.f;
            #pragma unroll
            for (int i = 0; i < 5; ++i) {
                int d = lane + 64 * i;
                if (d < 300) s += tanh_fast(cr[i] + sA[m * 300 + d]) * sV[d];
            }
            s = wred_sum(s);
            sc[m] = s;
        }
        float mx = sc[0];
        #pragma unroll
        for (int m = 1; m < 16; ++m) mx = fmaxf(mx, sc[m]);
        float den = 0.f;
        #pragma unroll
        for (int m = 0; m < 16; ++m) {
            sc[m] = __expf(sc[m] - mx);
            den += sc[m];
        }
        const float inv = 1.f / den;
        const float* lrow = lin + (size_t)(b * L1_ + l) * 300;
        float acc = 0.f;
        #pragma unroll
        for (int i = 0; i < 5; ++i) {
            int d = lane + 64 * i;
            if (d < 300) {
                float cd = 0.f;
                #pragma unroll
                for (int m = 0; m < 16; ++m) cd += sc[m] * sE[m * 300 + d];
                acc += tanh_fast(lrow[d] + cd * inv) * sW[d];
            }
        }
        acc = wred_sum(acc);
        if (lane == 0) blogit[b * L1_ + l] = acc + bvw;
    }
}

// ---------------- beta softmax over L1=512 per batch ----------------
__global__ __launch_bounds__(256) void beta_softmax_kernel(const float* __restrict__ x,
                                                           float* __restrict__ y) {
    const int b = blockIdx.x, tid = threadIdx.x;
    __shared__ float red[4];
    const int wave = tid >> 6, lane = tid & 63;
    float v0 = x[b * 512 + tid];
    float v1 = x[b * 512 + 256 + tid];
    float m = wred_max(fmaxf(v0, v1));
    if (lane == 0) red[wave] = m;
    __syncthreads();
    m = fmaxf(fmaxf(red[0], red[1]), fmaxf(red[2], red[3]));
    float e0 = __expf(v0 - m), e1 = __expf(v1 - m);
    float s = wred_sum(e0 + e1);
    __syncthreads();
    if (lane == 0) red[wave] = s;
    __syncthreads();
    s = red[0] + red[1] + red[2] + red[3];
    const float inv = 1.f / s;
    y[b * 512 + tid] = e0 * inv;
    y[b * 512 + 256 + tid] = e1 * inv;
}

// ---------------- GRU: one block per (batch, direction), persistent 512 steps ----------------
__global__ __launch_bounds__(256) void gru_kernel(const float* __restrict__ xg_f,
                                                  const float* __restrict__ xg_b,
                                                  const float* __restrict__ whhT_f,
                                                  const float* __restrict__ whhT_b,
                                                  const float* __restrict__ bhh_f,
                                                  const float* __restrict__ bhh_b,
                                                  const float* __restrict__ beta,
                                                  float* __restrict__ senti) {
    const int b = blockIdx.x;
    const int rev = blockIdx.y;
    const float* xg = rev ? xg_b : xg_f;
    const float* whhT = rev ? whhT_b : whhT_f;
    const float* bhh = rev ? bhh_b : bhh_f;

    __shared__ __align__(16) float h[300];
    __shared__ float g[900];
    const int tid = threadIdx.x;
    for (int i = tid; i < 300; i += 256) h[i] = 0.f;
    float sacc0 = 0.f, sacc1 = 0.f;
    const int r0 = tid * 4;  // 4 consecutive gate-rows per thread, tid < 225 active
    float bh0 = 0.f, bh1 = 0.f, bh2 = 0.f, bh3 = 0.f;
    if (r0 < 900) {
        bh0 = bhh[r0]; bh1 = bhh[r0 + 1]; bh2 = bhh[r0 + 2]; bh3 = bhh[r0 + 3];
    }
    __syncthreads();

    for (int step = 0; step < 512; ++step) {
        const int t = rev ? (511 - step) : step;
        if (r0 < 900) {
            float a0 = bh0, a1 = bh1, a2 = bh2, a3 = bh3;
            const float* wp = whhT + r0;
            #pragma unroll 4
            for (int k = 0; k < 300; k += 4) {
                const float4 hv = *reinterpret_cast<const float4*>(&h[k]);
                const float* wk = wp + (size_t)k * 900;
                float4 w;
                w = *reinterpret_cast<const float4*>(wk);
                a0 += hv.x * w.x; a1 += hv.x * w.y; a2 += hv.x * w.z; a3 += hv.x * w.w;
                w = *reinterpret_cast<const float4*>(wk + 900);
                a0 += hv.y * w.x; a1 += hv.y * w.y; a2 += hv.y * w.z; a3 += hv.y * w.w;
                w = *reinterpret_cast<const float4*>(wk + 1800);
                a0 += hv.z * w.x; a1 += hv.z * w.y; a2 += hv.z * w.z; a3 += hv.z * w.w;
                w = *reinterpret_cast<const float4*>(wk + 2700);
                a0 += hv.w * w.x; a1 += hv.w * w.y; a2 += hv.w * w.z; a3 += hv.w * w.w;
            }
            g[r0] = a0; g[r0 + 1] = a1; g[r0 + 2] = a2; g[r0 + 3] = a3;
        }
        __syncthreads();
        const float bt = beta[b * 512 + t];
        const float* xrow = xg + (size_t)(b * 512 + t) * 900;
        {
            const int e = tid;  // 0..255
            float rr = sigmoid_fast(xrow[e] + g[e]);
            float zz = sigmoid_fast(xrow[300 + e] + g[300 + e]);
            float nn = tanh_fast(xrow[600 + e] + rr * g[600 + e]);
            float hn = (1.f - zz) * nn + zz * h[e];
            h[e] = hn;
            sacc0 += bt * hn;
        }
        if (tid < 44) {
            const int e = 256 + tid;
            float rr = sigmoid_fast(xrow[e] + g[e]);
            float zz = sigmoid_fast(xrow[300 + e] + g[300 + e]);
            float nn = tanh_fast(xrow[600 + e] + rr * g[600 + e]);
            float hn = (1.f - zz) * nn + zz * h[e];
            h[e] = hn;
            sacc1 += bt * hn;
        }
        __syncthreads();
    }
    senti[b * 600 + rev * 300 + tid] = sacc0;
    if (tid < 44) senti[b * 600 + rev * 300 + 256 + tid] = sacc1;
}

// ---------------- final logits: (32,600) x (3,600)^T + outb ----------------
__global__ __launch_bounds__(64) void logits_kernel(const float* __restrict__ senti,
                                                    const float* __restrict__ outW,
                                                    const float* __restrict__ outb,
                                                    float* __restrict__ out) {
    const int b = blockIdx.x, lane = threadIdx.x;
    for (int c = 0; c < 3; ++c) {
        float s = 0.f;
        for (int hh = lane; hh < 600; hh += 64) s += senti[b * 600 + hh] * outW[c * 600 + hh];
        s = wred_sum(s);
        if (lane == 0) out[b * 3 + c] = s + outb[c];
    }
}

extern "C" void kernel_launch(void* const* d_in, const int* in_sizes, int n_in,
                              void* d_out, int out_size, void* d_ws, size_t ws_size,
                              hipStream_t stream) {
    const int* ctx_ids = (const int*)d_in[0];
    const int* asp_ids = (const int*)d_in[1];
    // d_in[2], d_in[3]: masks (all ones, unused by reference)
    const float* emb   = (const float*)d_in[4];
    const float* Wc    = (const float*)d_in[5];
    const float* Wa    = (const float*)d_in[6];
    const float* Vatt  = (const float*)d_in[7];
    const float* Wlin  = (const float*)d_in[8];
    const float* blin  = (const float*)d_in[9];
    const float* Vw    = (const float*)d_in[10];
    const float* bVw   = (const float*)d_in[11];
    const float* wih_f = (const float*)d_in[12];
    const float* whh_f = (const float*)d_in[13];
    const float* bih_f = (const float*)d_in[14];
    const float* bhh_f = (const float*)d_in[15];
    const float* wih_b = (const float*)d_in[16];
    const float* whh_b = (const float*)d_in[17];
    const float* bih_b = (const float*)d_in[18];
    const float* bhh_b = (const float*)d_in[19];
    const float* outW  = (const float*)d_in[20];
    const float* outb  = (const float*)d_in[21];
    float* ws = (float*)d_ws;

    size_t o = 0;
    float* ctx_emb = ws + o; o += (size_t)B_ * L1_ * D_;      // 4,915,200
    float* asp_emb = ws + o; o += (size_t)B_ * L2_ * D_;      //   153,600
    float* c_proj  = ws + o; o += (size_t)B_ * L1_ * D_;
    float* a_proj  = ws + o; o += (size_t)B_ * L2_ * D_;
    float* lin_buf = ws + o; o += (size_t)B_ * L1_ * D_;
    float* xg_f    = ws + o; o += (size_t)B_ * L1_ * 3 * H_;  // 14,745,600
    float* xg_b    = ws + o; o += (size_t)B_ * L1_ * 3 * H_;
    float* whhT_f  = ws + o; o += (size_t)300 * 900;
    float* whhT_b  = ws + o; o += (size_t)300 * 900;
    float* blogit  = ws + o; o += (size_t)B_ * L1_;
    float* beta    = ws + o; o += (size_t)B_ * L1_;
    float* senti   = ws + o; o += (size_t)B_ * 2 * H_;

    dim3 blk(256);
    const int tot_ctx = B_ * L1_ * 75;
    const int tot_asp = B_ * L2_ * 75;
    gather_kernel<<<dim3((tot_ctx + 255) / 256), blk, 0, stream>>>(emb, ctx_ids, ctx_emb, tot_ctx);
    gather_kernel<<<dim3((tot_asp + 255) / 256), blk, 0, stream>>>(emb, asp_ids, asp_emb, tot_asp);
    transpose_kernel<<<dim3((270000 + 255) / 256), blk, 0, stream>>>(whh_f, whhT_f);
    transpose_kernel<<<dim3((270000 + 255) / 256), blk, 0, stream>>>(whh_b, whhT_b);

    gemm_nt<<<dim3(16384 / 128, 5), blk, 0, stream>>>(ctx_emb, Wc, nullptr, c_proj, 16384, 300, 300);
    gemm_nt<<<dim3(16384 / 128, 5), blk, 0, stream>>>(ctx_emb, Wlin, blin, lin_buf, 16384, 300, 300);
    gemm_nt<<<dim3(512 / 128, 5), blk, 0, stream>>>(asp_emb, Wa, nullptr, a_proj, 512, 300, 300);
    gemm_nt<<<dim3(16384 / 128, 15), blk, 0, stream>>>(ctx_emb, wih_f, bih_f, xg_f, 16384, 900, 300);
    gemm_nt<<<dim3(16384 / 128, 15), blk, 0, stream>>>(ctx_emb, wih_b, bih_b, xg_b, 16384, 900, 300);

    attn_kernel<<<dim3(32, 32), blk, 0, stream>>>(c_proj, a_proj, asp_emb, lin_buf, Vatt, Vw, bVw, blogit);
    beta_softmax_kernel<<<dim3(32), blk, 0, stream>>>(blogit, beta);
    gru_kernel<<<dim3(32, 2), blk, 0, stream>>>(xg_f, xg_b, whhT_f, whhT_b, bhh_f, bhh_b, beta, senti);
    logits_kernel<<<dim3(32), dim3(64), 0, stream>>>(senti, outW, outb, (float*)d_out);
}